// Round 1
// baseline (12367.616 us; speedup 1.0000x reference)
//
#include <hip/hip_runtime.h>
#include <math.h>

#define PI_F 3.14159265358979323846f
#define TPB 64
#define STRIDE 193   // 64 c0 + 64 c1 + 64 h-stage + 1 pad (odd stride -> 2 lanes/bank, free)

__device__ __forceinline__ float frcp(float x)  { return __builtin_amdgcn_rcpf(x); }
__device__ __forceinline__ float fsig(float x)  { return frcp(1.0f + __expf(-x)); }
__device__ __forceinline__ float ftanhf(float x){ return 1.0f - 2.0f * frcp(1.0f + __expf(2.0f * x)); }

__global__ __launch_bounds__(TPB, 1)
void lstm_pinn(const float* __restrict__ xy,
               const float* __restrict__ w_ih0, const float* __restrict__ w_hh0, const float* __restrict__ b0,
               const float* __restrict__ w_ih1, const float* __restrict__ w_hh1, const float* __restrict__ b1,
               const float* __restrict__ fus_w, const float* __restrict__ fus_b,
               const float* __restrict__ res_w1, const float* __restrict__ res_b1,
               const float* __restrict__ res_w2, const float* __restrict__ res_b2,
               const float* __restrict__ head_w1, const float* __restrict__ head_b1,
               const float* __restrict__ head_w2, const float* __restrict__ head_b2,
               float* __restrict__ out, int N)
{
    __shared__ float lds[TPB * STRIDE];   // 49408 B -> 3 blocks/CU
    const int tid = blockIdx.x * TPB + threadIdx.x;
    if (tid >= N) return;
    float* __restrict__ my = lds + threadIdx.x * STRIDE;
    // my[0..63]=c0, my[64..127]=c1, my[128..191]=h staging

    const float x = xy[2 * tid + 0];
    const float y = xy[2 * tid + 1];
    const float x2 = x * x, y2 = y * y, xyv = x * y;
    const float spx = sinf(PI_F * x), cpx = cosf(PI_F * x);
    const float spy = sinf(PI_F * y), cpy = cosf(PI_F * y);

    float h0r[64], h1r[64];
    #pragma unroll
    for (int k = 0; k < 64; ++k) { h0r[k] = 0.0f; h1r[k] = 0.0f; }
    #pragma unroll
    for (int k = 0; k < 64; ++k) { my[k] = 0.0f; my[64 + k] = 0.0f; }

    for (int t = 0; t < 9; ++t) {
        float ft;
        switch (t) {           // t is wave-uniform -> scalar branch, no divergence
            case 0: ft = x;   break;
            case 1: ft = y;   break;
            case 2: ft = x2;  break;
            case 3: ft = y2;  break;
            case 4: ft = xyv; break;
            case 5: ft = spx; break;
            case 6: ft = cpx; break;
            case 7: ft = spy; break;
            default: ft = cpy; break;
        }

        // ---------------- layer 0 ----------------
        for (int j = 0; j < 64; ++j) {
            float ai = fmaf(ft, w_ih0[j],       b0[j]);
            float af = fmaf(ft, w_ih0[64 + j],  b0[64 + j]);
            float ag = fmaf(ft, w_ih0[128 + j], b0[128 + j]);
            float ao = fmaf(ft, w_ih0[192 + j], b0[192 + j]);
            const float* __restrict__ wr = w_hh0 + j * 64;
            #pragma unroll
            for (int k = 0; k < 64; ++k) {
                const float hk = h0r[k];
                ai = fmaf(hk, wr[k],            ai);
                af = fmaf(hk, wr[64 * 64 + k],  af);
                ag = fmaf(hk, wr[128 * 64 + k], ag);
                ao = fmaf(hk, wr[192 * 64 + k], ao);
            }
            const float ig = fsig(ai), fg = fsig(af), gg = ftanhf(ag), og = fsig(ao);
            const float c = fg * my[j] + ig * gg;
            my[j] = c;
            my[128 + j] = og * ftanhf(c);
        }
        #pragma unroll
        for (int k = 0; k < 64; ++k) h0r[k] = my[128 + k];

        // ---------------- layer 1 ----------------
        for (int j = 0; j < 64; ++j) {
            float ai = b1[j], af = b1[64 + j], ag = b1[128 + j], ao = b1[192 + j];
            const float* __restrict__ wi = w_ih1 + j * 64;
            const float* __restrict__ wh = w_hh1 + j * 64;
            #pragma unroll
            for (int k = 0; k < 64; ++k) {
                const float a0 = h0r[k];
                const float a1 = h1r[k];
                ai = fmaf(a0, wi[k],            ai);
                af = fmaf(a0, wi[64 * 64 + k],  af);
                ag = fmaf(a0, wi[128 * 64 + k], ag);
                ao = fmaf(a0, wi[192 * 64 + k], ao);
                ai = fmaf(a1, wh[k],            ai);
                af = fmaf(a1, wh[64 * 64 + k],  af);
                ag = fmaf(a1, wh[128 * 64 + k], ag);
                ao = fmaf(a1, wh[192 * 64 + k], ao);
            }
            const float ig = fsig(ai), fg = fsig(af), gg = ftanhf(ag), og = fsig(ao);
            const float c = fg * my[64 + j] + ig * gg;
            my[64 + j] = c;
            my[128 + j] = og * ftanhf(c);
        }
        #pragma unroll
        for (int k = 0; k < 64; ++k) h1r[k] = my[128 + k];
    }

    // ---------------- fused layer: z = tanh([h1, x, y] @ fus_w^T + fus_b) ----------------
    for (int j = 0; j < 64; ++j) {
        const float* __restrict__ wr = fus_w + j * 66;
        float a = fmaf(x, wr[64], fus_b[j]);
        a = fmaf(y, wr[65], a);
        #pragma unroll
        for (int k = 0; k < 64; ++k) a = fmaf(h1r[k], wr[k], a);
        my[128 + j] = ftanhf(a);
    }
    float z[64];
    #pragma unroll
    for (int k = 0; k < 64; ++k) z[k] = my[128 + k];

    // ---------------- 3 residual blocks ----------------
    for (int r = 0; r < 3; ++r) {
        const float* __restrict__ W1 = res_w1 + r * 64 * 64;
        const float* __restrict__ B1 = res_b1 + r * 64;
        const float* __restrict__ W2 = res_w2 + r * 64 * 64;
        const float* __restrict__ B2 = res_b2 + r * 64;
        for (int j = 0; j < 64; ++j) {
            float a = B1[j];
            const float* __restrict__ wr = W1 + j * 64;
            #pragma unroll
            for (int k = 0; k < 64; ++k) a = fmaf(z[k], wr[k], a);
            my[128 + j] = ftanhf(a);
        }
        float tt[64];
        #pragma unroll
        for (int k = 0; k < 64; ++k) tt[k] = my[128 + k];
        for (int j = 0; j < 64; ++j) {
            float a = B2[j];
            const float* __restrict__ wr = W2 + j * 64;
            #pragma unroll
            for (int k = 0; k < 64; ++k) a = fmaf(tt[k], wr[k], a);
            my[128 + j] = ftanhf(a);
        }
        #pragma unroll
        for (int k = 0; k < 64; ++k) z[k] += my[128 + k];
    }

    // ---------------- head ----------------
    for (int j = 0; j < 64; ++j) {
        float a = head_b1[j];
        const float* __restrict__ wr = head_w1 + j * 64;
        #pragma unroll
        for (int k = 0; k < 64; ++k) a = fmaf(z[k], wr[k], a);
        my[128 + j] = ftanhf(a);
    }
    float hh[64];
    #pragma unroll
    for (int k = 0; k < 64; ++k) hh[k] = my[128 + k];
    #pragma unroll
    for (int q = 0; q < 5; ++q) {
        float a = head_b2[q];
        const float* __restrict__ wr = head_w2 + q * 64;
        #pragma unroll
        for (int k = 0; k < 64; ++k) a = fmaf(hh[k], wr[k], a);
        out[tid * 5 + q] = a;
    }
}

extern "C" void kernel_launch(void* const* d_in, const int* in_sizes, int n_in,
                              void* d_out, int out_size, void* d_ws, size_t ws_size,
                              hipStream_t stream) {
    const float* xy      = (const float*)d_in[0];
    const float* w_ih0   = (const float*)d_in[1];
    const float* w_hh0   = (const float*)d_in[2];
    const float* b0      = (const float*)d_in[3];
    const float* w_ih1   = (const float*)d_in[4];
    const float* w_hh1   = (const float*)d_in[5];
    const float* b1      = (const float*)d_in[6];
    const float* fus_w   = (const float*)d_in[7];
    const float* fus_b   = (const float*)d_in[8];
    const float* res_w1  = (const float*)d_in[9];
    const float* res_b1  = (const float*)d_in[10];
    const float* res_w2  = (const float*)d_in[11];
    const float* res_b2  = (const float*)d_in[12];
    const float* head_w1 = (const float*)d_in[13];
    const float* head_b1 = (const float*)d_in[14];
    const float* head_w2 = (const float*)d_in[15];
    const float* head_b2 = (const float*)d_in[16];

    const int N = in_sizes[0] / 2;
    const int grid = (N + TPB - 1) / TPB;
    lstm_pinn<<<dim3(grid), dim3(TPB), 0, stream>>>(
        xy, w_ih0, w_hh0, b0, w_ih1, w_hh1, b1,
        fus_w, fus_b, res_w1, res_b1, res_w2, res_b2,
        head_w1, head_b1, head_w2, head_b2,
        (float*)d_out, N);
}

// Round 2
// 6961.673 us; speedup vs baseline: 1.7765x; 1.7765x over previous
//
#include <hip/hip_runtime.h>
#include <math.h>

#define PI_F 3.14159265358979323846f
#define TPB 64
#define LSTRIDE 65     // odd stride -> 2 lanes/bank on LDS, conflict-free
#define STRIDE 193     // fallback kernel (round-1) per-thread LDS stride

__device__ __forceinline__ float frcp(float x)  { return __builtin_amdgcn_rcpf(x); }
__device__ __forceinline__ float fsig(float x)  { return frcp(1.0f + __expf(-x)); }
__device__ __forceinline__ float ftanhf(float x){ return 1.0f - 2.0f * frcp(1.0f + __expf(2.0f * x)); }

// One LSTM timestep for both layers. c-state streams through global (cws),
// h-state lives in registers, 64-float h staging in LDS.
template<bool FIRST>
__device__ __forceinline__ void timestep(
    float ft, float (&h0r)[64], float (&h1r)[64],
    const float* __restrict__ w_ih0, const float* __restrict__ w_hh0, const float* __restrict__ b0,
    const float* __restrict__ w_ih1, const float* __restrict__ w_hh1, const float* __restrict__ b1,
    float* __restrict__ c0p, float* __restrict__ c1p,   // base + tid; element j at [j*N]
    float* __restrict__ stage, int N)
{
    // ---------------- layer 0 ----------------
    #pragma unroll 1
    for (int j = 0; j < 64; ++j) {
        float cold = 0.0f;
        if (!FIRST) cold = c0p[j * N];              // issued early, used after 256 fmas
        float ai = fmaf(ft, w_ih0[j],       b0[j]);
        float af = fmaf(ft, w_ih0[64 + j],  b0[64 + j]);
        float ag = fmaf(ft, w_ih0[128 + j], b0[128 + j]);
        float ao = fmaf(ft, w_ih0[192 + j], b0[192 + j]);
        const float* __restrict__ wr = w_hh0 + j * 64;
        #pragma unroll
        for (int k = 0; k < 64; ++k) {
            const float hk = h0r[k];
            ai = fmaf(hk, wr[k],            ai);
            af = fmaf(hk, wr[64 * 64 + k],  af);
            ag = fmaf(hk, wr[128 * 64 + k], ag);
            ao = fmaf(hk, wr[192 * 64 + k], ao);
        }
        const float ig = fsig(ai), fg = fsig(af), gg = ftanhf(ag), og = fsig(ao);
        const float c = FIRST ? (ig * gg) : fmaf(fg, cold, ig * gg);
        c0p[j * N] = c;
        stage[j] = og * ftanhf(c);
    }
    #pragma unroll
    for (int k = 0; k < 64; ++k) h0r[k] = stage[k];

    // ---------------- layer 1 ----------------
    #pragma unroll 1
    for (int j = 0; j < 64; ++j) {
        float cold = 0.0f;
        if (!FIRST) cold = c1p[j * N];
        float ai = b1[j], af = b1[64 + j], ag = b1[128 + j], ao = b1[192 + j];
        const float* __restrict__ wi = w_ih1 + j * 64;
        const float* __restrict__ wh = w_hh1 + j * 64;
        #pragma unroll
        for (int k = 0; k < 64; ++k) {
            const float a0 = h0r[k];
            const float a1 = h1r[k];
            ai = fmaf(a0, wi[k],            ai);
            af = fmaf(a0, wi[64 * 64 + k],  af);
            ag = fmaf(a0, wi[128 * 64 + k], ag);
            ao = fmaf(a0, wi[192 * 64 + k], ao);
            ai = fmaf(a1, wh[k],            ai);
            af = fmaf(a1, wh[64 * 64 + k],  af);
            ag = fmaf(a1, wh[128 * 64 + k], ag);
            ao = fmaf(a1, wh[192 * 64 + k], ao);
        }
        const float ig = fsig(ai), fg = fsig(af), gg = ftanhf(ag), og = fsig(ao);
        const float c = FIRST ? (ig * gg) : fmaf(fg, cold, ig * gg);
        c1p[j * N] = c;
        stage[j] = og * ftanhf(c);
    }
    #pragma unroll
    for (int k = 0; k < 64; ++k) h1r[k] = stage[k];
}

__global__ __launch_bounds__(TPB, 3)   // cap VGPR at ~170 (3 waves/SIMD)
void lstm_pinn_ws(const float* __restrict__ xy,
                  const float* __restrict__ w_ih0, const float* __restrict__ w_hh0, const float* __restrict__ b0,
                  const float* __restrict__ w_ih1, const float* __restrict__ w_hh1, const float* __restrict__ b1,
                  const float* __restrict__ fus_w, const float* __restrict__ fus_b,
                  const float* __restrict__ res_w1, const float* __restrict__ res_b1,
                  const float* __restrict__ res_w2, const float* __restrict__ res_b2,
                  const float* __restrict__ head_w1, const float* __restrict__ head_b1,
                  const float* __restrict__ head_w2, const float* __restrict__ head_b2,
                  float* __restrict__ out, float* __restrict__ cws, int N)
{
    __shared__ float lds[TPB * LSTRIDE];   // 16640 B -> 9 blocks/CU
    const int tid = blockIdx.x * TPB + threadIdx.x;
    if (tid >= N) return;
    float* __restrict__ stage = lds + threadIdx.x * LSTRIDE;
    float* __restrict__ c0p = cws + tid;
    float* __restrict__ c1p = cws + (size_t)64 * N + tid;

    const float x = xy[2 * tid + 0];
    const float y = xy[2 * tid + 1];
    const float x2 = x * x, y2 = y * y, xyv = x * y;
    const float spx = sinf(PI_F * x), cpx = cosf(PI_F * x);
    const float spy = sinf(PI_F * y), cpy = cosf(PI_F * y);

    float h0r[64], h1r[64];
    #pragma unroll
    for (int k = 0; k < 64; ++k) { h0r[k] = 0.0f; h1r[k] = 0.0f; }

    timestep<true>(x, h0r, h1r, w_ih0, w_hh0, b0, w_ih1, w_hh1, b1, c0p, c1p, stage, N);
    #pragma unroll 1
    for (int t = 1; t < 9; ++t) {
        float ft;
        switch (t) {           // wave-uniform -> scalar branch
            case 1: ft = y;   break;
            case 2: ft = x2;  break;
            case 3: ft = y2;  break;
            case 4: ft = xyv; break;
            case 5: ft = spx; break;
            case 6: ft = cpx; break;
            case 7: ft = spy; break;
            default: ft = cpy; break;
        }
        timestep<false>(ft, h0r, h1r, w_ih0, w_hh0, b0, w_ih1, w_hh1, b1, c0p, c1p, stage, N);
    }

    // ---------------- fused layer ----------------
    #pragma unroll 1
    for (int j = 0; j < 64; ++j) {
        const float* __restrict__ wr = fus_w + j * 66;
        float a = fmaf(x, wr[64], fus_b[j]);
        a = fmaf(y, wr[65], a);
        #pragma unroll
        for (int k = 0; k < 64; ++k) a = fmaf(h1r[k], wr[k], a);
        stage[j] = ftanhf(a);
    }
    float z[64];
    #pragma unroll
    for (int k = 0; k < 64; ++k) z[k] = stage[k];

    // ---------------- 3 residual blocks ----------------
    #pragma unroll 1
    for (int r = 0; r < 3; ++r) {
        const float* __restrict__ W1 = res_w1 + r * 64 * 64;
        const float* __restrict__ B1 = res_b1 + r * 64;
        const float* __restrict__ W2 = res_w2 + r * 64 * 64;
        const float* __restrict__ B2 = res_b2 + r * 64;
        #pragma unroll 1
        for (int j = 0; j < 64; ++j) {
            float a = B1[j];
            const float* __restrict__ wr = W1 + j * 64;
            #pragma unroll
            for (int k = 0; k < 64; ++k) a = fmaf(z[k], wr[k], a);
            stage[j] = ftanhf(a);
        }
        float tt[64];
        #pragma unroll
        for (int k = 0; k < 64; ++k) tt[k] = stage[k];
        #pragma unroll 1
        for (int j = 0; j < 64; ++j) {
            float a = B2[j];
            const float* __restrict__ wr = W2 + j * 64;
            #pragma unroll
            for (int k = 0; k < 64; ++k) a = fmaf(tt[k], wr[k], a);
            stage[j] = ftanhf(a);
        }
        #pragma unroll
        for (int k = 0; k < 64; ++k) z[k] += stage[k];
    }

    // ---------------- head ----------------
    #pragma unroll 1
    for (int j = 0; j < 64; ++j) {
        float a = head_b1[j];
        const float* __restrict__ wr = head_w1 + j * 64;
        #pragma unroll
        for (int k = 0; k < 64; ++k) a = fmaf(z[k], wr[k], a);
        stage[j] = ftanhf(a);
    }
    float hh[64];
    #pragma unroll
    for (int k = 0; k < 64; ++k) hh[k] = stage[k];
    #pragma unroll
    for (int q = 0; q < 5; ++q) {
        float a = head_b2[q];
        const float* __restrict__ wr = head_w2 + q * 64;
        #pragma unroll
        for (int k = 0; k < 64; ++k) a = fmaf(hh[k], wr[k], a);
        out[tid * 5 + q] = a;
    }
}

// ---------- round-1 fallback (used only if ws_size < 128 MB) ----------
__global__ __launch_bounds__(TPB, 1)
void lstm_pinn_small(const float* __restrict__ xy,
               const float* __restrict__ w_ih0, const float* __restrict__ w_hh0, const float* __restrict__ b0,
               const float* __restrict__ w_ih1, const float* __restrict__ w_hh1, const float* __restrict__ b1,
               const float* __restrict__ fus_w, const float* __restrict__ fus_b,
               const float* __restrict__ res_w1, const float* __restrict__ res_b1,
               const float* __restrict__ res_w2, const float* __restrict__ res_b2,
               const float* __restrict__ head_w1, const float* __restrict__ head_b1,
               const float* __restrict__ head_w2, const float* __restrict__ head_b2,
               float* __restrict__ out, int N)
{
    __shared__ float lds[TPB * STRIDE];
    const int tid = blockIdx.x * TPB + threadIdx.x;
    if (tid >= N) return;
    float* __restrict__ my = lds + threadIdx.x * STRIDE;

    const float x = xy[2 * tid + 0];
    const float y = xy[2 * tid + 1];
    const float x2 = x * x, y2 = y * y, xyv = x * y;
    const float spx = sinf(PI_F * x), cpx = cosf(PI_F * x);
    const float spy = sinf(PI_F * y), cpy = cosf(PI_F * y);

    float h0r[64], h1r[64];
    #pragma unroll
    for (int k = 0; k < 64; ++k) { h0r[k] = 0.0f; h1r[k] = 0.0f; }
    #pragma unroll
    for (int k = 0; k < 64; ++k) { my[k] = 0.0f; my[64 + k] = 0.0f; }

    for (int t = 0; t < 9; ++t) {
        float ft;
        switch (t) {
            case 0: ft = x;   break;
            case 1: ft = y;   break;
            case 2: ft = x2;  break;
            case 3: ft = y2;  break;
            case 4: ft = xyv; break;
            case 5: ft = spx; break;
            case 6: ft = cpx; break;
            case 7: ft = spy; break;
            default: ft = cpy; break;
        }
        for (int j = 0; j < 64; ++j) {
            float ai = fmaf(ft, w_ih0[j],       b0[j]);
            float af = fmaf(ft, w_ih0[64 + j],  b0[64 + j]);
            float ag = fmaf(ft, w_ih0[128 + j], b0[128 + j]);
            float ao = fmaf(ft, w_ih0[192 + j], b0[192 + j]);
            const float* __restrict__ wr = w_hh0 + j * 64;
            #pragma unroll
            for (int k = 0; k < 64; ++k) {
                const float hk = h0r[k];
                ai = fmaf(hk, wr[k],            ai);
                af = fmaf(hk, wr[64 * 64 + k],  af);
                ag = fmaf(hk, wr[128 * 64 + k], ag);
                ao = fmaf(hk, wr[192 * 64 + k], ao);
            }
            const float ig = fsig(ai), fg = fsig(af), gg = ftanhf(ag), og = fsig(ao);
            const float c = fg * my[j] + ig * gg;
            my[j] = c;
            my[128 + j] = og * ftanhf(c);
        }
        #pragma unroll
        for (int k = 0; k < 64; ++k) h0r[k] = my[128 + k];

        for (int j = 0; j < 64; ++j) {
            float ai = b1[j], af = b1[64 + j], ag = b1[128 + j], ao = b1[192 + j];
            const float* __restrict__ wi = w_ih1 + j * 64;
            const float* __restrict__ wh = w_hh1 + j * 64;
            #pragma unroll
            for (int k = 0; k < 64; ++k) {
                const float a0 = h0r[k];
                const float a1 = h1r[k];
                ai = fmaf(a0, wi[k],            ai);
                af = fmaf(a0, wi[64 * 64 + k],  af);
                ag = fmaf(a0, wi[128 * 64 + k], ag);
                ao = fmaf(a0, wi[192 * 64 + k], ao);
                ai = fmaf(a1, wh[k],            ai);
                af = fmaf(a1, wh[64 * 64 + k],  af);
                ag = fmaf(a1, wh[128 * 64 + k], ag);
                ao = fmaf(a1, wh[192 * 64 + k], ao);
            }
            const float ig = fsig(ai), fg = fsig(af), gg = ftanhf(ag), og = fsig(ao);
            const float c = fg * my[64 + j] + ig * gg;
            my[64 + j] = c;
            my[128 + j] = og * ftanhf(c);
        }
        #pragma unroll
        for (int k = 0; k < 64; ++k) h1r[k] = my[128 + k];
    }

    for (int j = 0; j < 64; ++j) {
        const float* __restrict__ wr = fus_w + j * 66;
        float a = fmaf(x, wr[64], fus_b[j]);
        a = fmaf(y, wr[65], a);
        #pragma unroll
        for (int k = 0; k < 64; ++k) a = fmaf(h1r[k], wr[k], a);
        my[128 + j] = ftanhf(a);
    }
    float z[64];
    #pragma unroll
    for (int k = 0; k < 64; ++k) z[k] = my[128 + k];

    for (int r = 0; r < 3; ++r) {
        const float* __restrict__ W1 = res_w1 + r * 64 * 64;
        const float* __restrict__ B1 = res_b1 + r * 64;
        const float* __restrict__ W2 = res_w2 + r * 64 * 64;
        const float* __restrict__ B2 = res_b2 + r * 64;
        for (int j = 0; j < 64; ++j) {
            float a = B1[j];
            const float* __restrict__ wr = W1 + j * 64;
            #pragma unroll
            for (int k = 0; k < 64; ++k) a = fmaf(z[k], wr[k], a);
            my[128 + j] = ftanhf(a);
        }
        float tt[64];
        #pragma unroll
        for (int k = 0; k < 64; ++k) tt[k] = my[128 + k];
        for (int j = 0; j < 64; ++j) {
            float a = B2[j];
            const float* __restrict__ wr = W2 + j * 64;
            #pragma unroll
            for (int k = 0; k < 64; ++k) a = fmaf(tt[k], wr[k], a);
            my[128 + j] = ftanhf(a);
        }
        #pragma unroll
        for (int k = 0; k < 64; ++k) z[k] += my[128 + k];
    }

    for (int j = 0; j < 64; ++j) {
        float a = head_b1[j];
        const float* __restrict__ wr = head_w1 + j * 64;
        #pragma unroll
        for (int k = 0; k < 64; ++k) a = fmaf(z[k], wr[k], a);
        my[128 + j] = ftanhf(a);
    }
    float hh[64];
    #pragma unroll
    for (int k = 0; k < 64; ++k) hh[k] = my[128 + k];
    #pragma unroll
    for (int q = 0; q < 5; ++q) {
        float a = head_b2[q];
        const float* __restrict__ wr = head_w2 + q * 64;
        #pragma unroll
        for (int k = 0; k < 64; ++k) a = fmaf(hh[k], wr[k], a);
        out[tid * 5 + q] = a;
    }
}

extern "C" void kernel_launch(void* const* d_in, const int* in_sizes, int n_in,
                              void* d_out, int out_size, void* d_ws, size_t ws_size,
                              hipStream_t stream) {
    const float* xy      = (const float*)d_in[0];
    const float* w_ih0   = (const float*)d_in[1];
    const float* w_hh0   = (const float*)d_in[2];
    const float* b0      = (const float*)d_in[3];
    const float* w_ih1   = (const float*)d_in[4];
    const float* w_hh1   = (const float*)d_in[5];
    const float* b1      = (const float*)d_in[6];
    const float* fus_w   = (const float*)d_in[7];
    const float* fus_b   = (const float*)d_in[8];
    const float* res_w1  = (const float*)d_in[9];
    const float* res_b1  = (const float*)d_in[10];
    const float* res_w2  = (const float*)d_in[11];
    const float* res_b2  = (const float*)d_in[12];
    const float* head_w1 = (const float*)d_in[13];
    const float* head_b1 = (const float*)d_in[14];
    const float* head_w2 = (const float*)d_in[15];
    const float* head_b2 = (const float*)d_in[16];

    const int N = in_sizes[0] / 2;
    const int grid = (N + TPB - 1) / TPB;
    const size_t ws_needed = (size_t)2 * 64 * (size_t)N * sizeof(float);  // c0,c1

    if (ws_size >= ws_needed) {
        lstm_pinn_ws<<<dim3(grid), dim3(TPB), 0, stream>>>(
            xy, w_ih0, w_hh0, b0, w_ih1, w_hh1, b1,
            fus_w, fus_b, res_w1, res_b1, res_w2, res_b2,
            head_w1, head_b1, head_w2, head_b2,
            (float*)d_out, (float*)d_ws, N);
    } else {
        lstm_pinn_small<<<dim3(grid), dim3(TPB), 0, stream>>>(
            xy, w_ih0, w_hh0, b0, w_ih1, w_hh1, b1,
            fus_w, fus_b, res_w1, res_b1, res_w2, res_b2,
            head_w1, head_b1, head_w2, head_b2,
            (float*)d_out, N);
    }
}

// Round 3
// 773.027 us; speedup vs baseline: 15.9989x; 9.0057x over previous
//
#include <hip/hip_runtime.h>
#include <math.h>

#define PI_F 3.14159265358979323846f
#define WAVES 12
#define TPB (WAVES*64)

typedef _Float16 half_t;
typedef __attribute__((ext_vector_type(8))) _Float16 f16x8;
typedef __attribute__((ext_vector_type(4))) float f32x4;

union F16x8U { f16x8 v; unsigned int u[4]; half_t h[8]; };

__device__ __forceinline__ float frcp(float x)  { return __builtin_amdgcn_rcpf(x); }
__device__ __forceinline__ float fsig(float x)  { return frcp(1.0f + __expf(-x)); }
__device__ __forceinline__ float ftanh(float x) { return 1.0f - 2.0f * frcp(1.0f + __expf(2.0f * x)); }

#define MFMA16(a,b,c) __builtin_amdgcn_mfma_f32_16x16x32_f16((a),(b),(c),0,0,0)

// Fragment conventions (gfx950 mfma_f32_16x16x32_f16), lane l = tid&63:
//  A[16x32]: row = l&15,          k = (l>>4)*8 + i   (i = elem 0..7)
//  B[32x16]: col = l&15,          k = (l>>4)*8 + i
//  D[16x16]: col = l&15,          row = (l>>4)*4 + r (r = reg 0..3)   [verified m89/m91]

__global__ __launch_bounds__(TPB, 3)
void lstm_pinn_mfma(const float* __restrict__ xy,
                    const float* __restrict__ w_ih0, const float* __restrict__ w_hh0, const float* __restrict__ b0,
                    const float* __restrict__ w_ih1, const float* __restrict__ w_hh1, const float* __restrict__ b1,
                    const float* __restrict__ fus_w, const float* __restrict__ fus_b,
                    const float* __restrict__ res_w1, const float* __restrict__ res_b1,
                    const float* __restrict__ res_w2, const float* __restrict__ res_b2,
                    const float* __restrict__ head_w1, const float* __restrict__ head_b1,
                    const float* __restrict__ head_w2, const float* __restrict__ head_b2,
                    float* __restrict__ out, int N)
{
    // B-fragments of the 3 recurrent matrices, fp16, frag-order: [mat][cb][kb][lane][8]
    __shared__ __align__(16) half_t wlds[3][16][2][64][8];          // 96 KB
    // per-wave activation tiles in A-fragment order: [wave][buf][kb][lane][8]
    __shared__ __align__(16) half_t hfrag[WAVES][2][2][64][8];      // 48 KB

    const int lane = threadIdx.x & 63;
    const int wid  = threadIdx.x >> 6;
    const int cc   = lane & 15;
    const int qq   = lane >> 4;

    // ---- stage weights as packed B-fragments (whole block cooperates) ----
    #pragma unroll
    for (int it = 0; it < 8; ++it) {
        int fl   = threadIdx.x + it * TPB;        // 0 .. 6143
        int ln   = fl & 63;
        int rest = fl >> 6;
        int kb   = rest & 1;
        int cb   = (rest >> 1) & 15;
        int mat  = rest >> 5;                     // 0,1,2
        const float* W = (mat == 0) ? w_hh0 : ((mat == 1) ? w_ih1 : w_hh1);
        const float* src = W + (cb * 16 + (ln & 15)) * 64 + kb * 32 + (ln >> 4) * 8;
        F16x8U tmp;
        #pragma unroll
        for (int i = 0; i < 8; ++i) tmp.h[i] = (half_t)src[i];
        *(f16x8*)&wlds[mat][cb][kb][ln][0] = tmp.v;
    }
    __syncthreads();

    const int S = (blockIdx.x * WAVES + wid) * 16;   // 16 samples per wave
    if (S >= N) return;

    // ---- per-lane features for sample S+cc (A-frag rows are l&15) ----
    const float fx = xy[2 * (S + cc) + 0];
    const float fy = xy[2 * (S + cc) + 1];
    float feat[9];
    feat[0] = fx; feat[1] = fy; feat[2] = fx * fx; feat[3] = fy * fy; feat[4] = fx * fy;
    feat[5] = sinf(PI_F * fx); feat[6] = cosf(PI_F * fx);
    feat[7] = sinf(PI_F * fy); feat[8] = cosf(PI_F * fy);

    // layer-0 augmented B payload: k'=0 -> w_ih0[col], k'=1 -> b0[col] (q==0 lanes only)
    unsigned int wb0[16];
    #pragma unroll
    for (int cb = 0; cb < 16; ++cb) {
        F16x8U t; t.u[0] = 0;
        t.h[0] = (half_t)w_ih0[cb * 16 + cc];
        t.h[1] = (half_t)b0[cb * 16 + cc];
        wb0[cb] = (qq == 0) ? t.u[0] : 0u;
    }
    float b1r[16];
    #pragma unroll
    for (int cb = 0; cb < 16; ++cb) b1r[cb] = b1[cb * 16 + cc];

    // ---- zero h-frags and c-state ----
    {
        F16x8U Z; Z.u[0] = Z.u[1] = Z.u[2] = Z.u[3] = 0;
        *(f16x8*)&hfrag[wid][0][0][lane][0] = Z.v;
        *(f16x8*)&hfrag[wid][0][1][lane][0] = Z.v;
        *(f16x8*)&hfrag[wid][1][0][lane][0] = Z.v;
        *(f16x8*)&hfrag[wid][1][1][lane][0] = Z.v;
    }
    float c0s[4][4], c1s[4][4];
    #pragma unroll
    for (int a = 0; a < 4; ++a)
        #pragma unroll
        for (int b = 0; b < 4; ++b) { c0s[a][b] = 0.0f; c1s[a][b] = 0.0f; }

    asm volatile("" ::: "memory");

    // ---- 9 timesteps ----
    #pragma unroll 1
    for (int t = 0; t < 9; ++t) {
        float ftv;
        switch (t) {
            case 0: ftv = feat[0]; break;  case 1: ftv = feat[1]; break;
            case 2: ftv = feat[2]; break;  case 3: ftv = feat[3]; break;
            case 4: ftv = feat[4]; break;  case 5: ftv = feat[5]; break;
            case 6: ftv = feat[6]; break;  case 7: ftv = feat[7]; break;
            default: ftv = feat[8]; break;
        }
        // augmented A frag: k'=0 -> ft[row], k'=1 -> 1
        F16x8U AG; AG.u[0] = AG.u[1] = AG.u[2] = AG.u[3] = 0;
        if (qq == 0) { AG.h[0] = (half_t)ftv; AG.h[1] = (half_t)1.0f; }

        // ------- layer 0: G = ft*wih0 + b0 + h0 @ Whh0^T -------
        f16x8 a00 = *(const f16x8*)&hfrag[wid][0][0][lane][0];
        f16x8 a01 = *(const f16x8*)&hfrag[wid][0][1][lane][0];
        #pragma unroll
        for (int jj = 0; jj < 4; ++jj) {
            f32x4 acc[4];
            #pragma unroll
            for (int g = 0; g < 4; ++g) {
                const int cb = jj + 4 * g;
                F16x8U BA; BA.u[0] = wb0[cb]; BA.u[1] = 0; BA.u[2] = 0; BA.u[3] = 0;
                f32x4 a = {0.f, 0.f, 0.f, 0.f};
                a = MFMA16(AG.v, BA.v, a);
                f16x8 bf0 = *(const f16x8*)&wlds[0][cb][0][lane][0];
                f16x8 bf1 = *(const f16x8*)&wlds[0][cb][1][lane][0];
                a = MFMA16(a00, bf0, a);
                a = MFMA16(a01, bf1, a);
                acc[g] = a;
            }
            const int kb = jj >> 1;
            half_t* hp = &hfrag[wid][0][kb][0][0];
            const int lb = (4 * qq + 16 * ((2 * jj + (cc >> 3)) & 3)) * 8 + (cc & 7);
            #pragma unroll
            for (int r = 0; r < 4; ++r) {
                float gi = fsig(acc[0][r]);
                float gf = fsig(acc[1][r]);
                float gg = ftanh(acc[2][r]);
                float go = fsig(acc[3][r]);
                float cv = gf * c0s[jj][r] + gi * gg;
                c0s[jj][r] = cv;
                hp[lb + 8 * r] = (half_t)(go * ftanh(cv));
            }
        }
        asm volatile("" ::: "memory");

        // ------- layer 1: G = b1 + h0 @ Wih1^T + h1 @ Whh1^T -------
        f16x8 a10 = *(const f16x8*)&hfrag[wid][0][0][lane][0];
        f16x8 a11 = *(const f16x8*)&hfrag[wid][0][1][lane][0];
        f16x8 a12 = *(const f16x8*)&hfrag[wid][1][0][lane][0];
        f16x8 a13 = *(const f16x8*)&hfrag[wid][1][1][lane][0];
        #pragma unroll
        for (int jj = 0; jj < 4; ++jj) {
            f32x4 acc[4];
            #pragma unroll
            for (int g = 0; g < 4; ++g) {
                const int cb = jj + 4 * g;
                f32x4 a = {b1r[cb], b1r[cb], b1r[cb], b1r[cb]};
                f16x8 bi0 = *(const f16x8*)&wlds[1][cb][0][lane][0];
                f16x8 bi1 = *(const f16x8*)&wlds[1][cb][1][lane][0];
                f16x8 bh0 = *(const f16x8*)&wlds[2][cb][0][lane][0];
                f16x8 bh1 = *(const f16x8*)&wlds[2][cb][1][lane][0];
                a = MFMA16(a10, bi0, a);
                a = MFMA16(a11, bi1, a);
                a = MFMA16(a12, bh0, a);
                a = MFMA16(a13, bh1, a);
                acc[g] = a;
            }
            const int kb = jj >> 1;
            half_t* hp = &hfrag[wid][1][kb][0][0];
            const int lb = (4 * qq + 16 * ((2 * jj + (cc >> 3)) & 3)) * 8 + (cc & 7);
            #pragma unroll
            for (int r = 0; r < 4; ++r) {
                float gi = fsig(acc[0][r]);
                float gf = fsig(acc[1][r]);
                float gg = ftanh(acc[2][r]);
                float go = fsig(acc[3][r]);
                float cv = gf * c1s[jj][r] + gi * gg;
                c1s[jj][r] = cv;
                hp[lb + 8 * r] = (half_t)(go * ftanh(cv));
            }
        }
        asm volatile("" ::: "memory");
    }

    // ================= epilogue (weights from global, L2-resident) =================
    // helper macro: write a [16][64] activation tile (vals[cb][r]) into frag buffer
#define WRITE_ACT(BUF, VALS) do {                                              \
        _Pragma("unroll")                                                      \
        for (int cb = 0; cb < 4; ++cb) {                                       \
            half_t* hp = &hfrag[wid][BUF][cb >> 1][0][0];                      \
            const int lb = (4*qq + 16*((2*cb + (cc>>3)) & 3))*8 + (cc & 7);    \
            _Pragma("unroll")                                                  \
            for (int r = 0; r < 4; ++r) hp[lb + 8*r] = (half_t)(VALS)[cb][r];  \
        }                                                                      \
        asm volatile("" ::: "memory");                                         \
    } while (0)

    // ---- fused: z = tanh([h1, x, y] @ fus_w^T + fus_b), fus_w is [64][66] ----
    float zz[4][4];
    {
        f16x8 e0 = *(const f16x8*)&hfrag[wid][1][0][lane][0];
        f16x8 e1 = *(const f16x8*)&hfrag[wid][1][1][lane][0];
        F16x8U AF; AF.u[0] = AF.u[1] = AF.u[2] = AF.u[3] = 0;
        if (qq == 0) { AF.h[0] = (half_t)feat[0]; AF.h[1] = (half_t)feat[1]; AF.h[2] = (half_t)1.0f; }
        #pragma unroll
        for (int cb = 0; cb < 4; ++cb) {
            const int row = cb * 16 + cc;
            F16x8U B0, B1, BB;
            #pragma unroll
            for (int i = 0; i < 8; ++i) {
                B0.h[i] = (half_t)fus_w[row * 66 + qq * 8 + i];
                B1.h[i] = (half_t)fus_w[row * 66 + 32 + qq * 8 + i];
            }
            BB.u[0] = BB.u[1] = BB.u[2] = BB.u[3] = 0;
            if (qq == 0) {
                BB.h[0] = (half_t)fus_w[row * 66 + 64];
                BB.h[1] = (half_t)fus_w[row * 66 + 65];
                BB.h[2] = (half_t)fus_b[row];
            }
            f32x4 a = {0.f, 0.f, 0.f, 0.f};
            a = MFMA16(e0, B0.v, a);
            a = MFMA16(e1, B1.v, a);
            a = MFMA16(AF.v, BB.v, a);
            #pragma unroll
            for (int r = 0; r < 4; ++r) zz[cb][r] = ftanh(a[r]);
        }
    }
    WRITE_ACT(0, zz);

    // ---- 3 residual blocks ----
    #pragma unroll 1
    for (int rb = 0; rb < 3; ++rb) {
        const float* W1 = res_w1 + rb * 4096;
        const float* B1p = res_b1 + rb * 64;
        const float* W2 = res_w2 + rb * 4096;
        const float* B2p = res_b2 + rb * 64;

        f16x8 za0 = *(const f16x8*)&hfrag[wid][0][0][lane][0];
        f16x8 za1 = *(const f16x8*)&hfrag[wid][0][1][lane][0];
        float tt[4][4];
        #pragma unroll
        for (int cb = 0; cb < 4; ++cb) {
            const int row = cb * 16 + cc;
            F16x8U B0, B1;
            #pragma unroll
            for (int i = 0; i < 8; ++i) {
                B0.h[i] = (half_t)W1[row * 64 + qq * 8 + i];
                B1.h[i] = (half_t)W1[row * 64 + 32 + qq * 8 + i];
            }
            float bb = B1p[row];
            f32x4 a = {bb, bb, bb, bb};
            a = MFMA16(za0, B0.v, a);
            a = MFMA16(za1, B1.v, a);
            #pragma unroll
            for (int r = 0; r < 4; ++r) tt[cb][r] = ftanh(a[r]);
        }
        WRITE_ACT(1, tt);

        f16x8 ta0 = *(const f16x8*)&hfrag[wid][1][0][lane][0];
        f16x8 ta1 = *(const f16x8*)&hfrag[wid][1][1][lane][0];
        #pragma unroll
        for (int cb = 0; cb < 4; ++cb) {
            const int row = cb * 16 + cc;
            F16x8U B0, B1;
            #pragma unroll
            for (int i = 0; i < 8; ++i) {
                B0.h[i] = (half_t)W2[row * 64 + qq * 8 + i];
                B1.h[i] = (half_t)W2[row * 64 + 32 + qq * 8 + i];
            }
            float bb = B2p[row];
            f32x4 a = {bb, bb, bb, bb};
            a = MFMA16(ta0, B0.v, a);
            a = MFMA16(ta1, B1.v, a);
            #pragma unroll
            for (int r = 0; r < 4; ++r) zz[cb][r] += ftanh(a[r]);
        }
        WRITE_ACT(0, zz);
    }

    // ---- head ----
    float hh[4][4];
    {
        f16x8 za0 = *(const f16x8*)&hfrag[wid][0][0][lane][0];
        f16x8 za1 = *(const f16x8*)&hfrag[wid][0][1][lane][0];
        #pragma unroll
        for (int cb = 0; cb < 4; ++cb) {
            const int row = cb * 16 + cc;
            F16x8U B0, B1;
            #pragma unroll
            for (int i = 0; i < 8; ++i) {
                B0.h[i] = (half_t)head_w1[row * 64 + qq * 8 + i];
                B1.h[i] = (half_t)head_w1[row * 64 + 32 + qq * 8 + i];
            }
            float bb = head_b1[row];
            f32x4 a = {bb, bb, bb, bb};
            a = MFMA16(za0, B0.v, a);
            a = MFMA16(za1, B1.v, a);
            #pragma unroll
            for (int r = 0; r < 4; ++r) hh[cb][r] = ftanh(a[r]);
        }
    }
    WRITE_ACT(1, hh);

    {
        f16x8 ha0 = *(const f16x8*)&hfrag[wid][1][0][lane][0];
        f16x8 ha1 = *(const f16x8*)&hfrag[wid][1][1][lane][0];
        F16x8U B0, B1;
        B0.u[0] = B0.u[1] = B0.u[2] = B0.u[3] = 0;
        B1.u[0] = B1.u[1] = B1.u[2] = B1.u[3] = 0;
        float bb = 0.0f;
        if (cc < 5) {
            #pragma unroll
            for (int i = 0; i < 8; ++i) {
                B0.h[i] = (half_t)head_w2[cc * 64 + qq * 8 + i];
                B1.h[i] = (half_t)head_w2[cc * 64 + 32 + qq * 8 + i];
            }
            bb = head_b2[cc];
        }
        f32x4 a = {bb, bb, bb, bb};
        a = MFMA16(ha0, B0.v, a);
        a = MFMA16(ha1, B1.v, a);
        if (cc < 5) {
            #pragma unroll
            for (int r = 0; r < 4; ++r)
                out[(S + 4 * qq + r) * 5 + cc] = a[r];
        }
    }
#undef WRITE_ACT
}

extern "C" void kernel_launch(void* const* d_in, const int* in_sizes, int n_in,
                              void* d_out, int out_size, void* d_ws, size_t ws_size,
                              hipStream_t stream) {
    const float* xy      = (const float*)d_in[0];
    const float* w_ih0   = (const float*)d_in[1];
    const float* w_hh0   = (const float*)d_in[2];
    const float* b0      = (const float*)d_in[3];
    const float* w_ih1   = (const float*)d_in[4];
    const float* w_hh1   = (const float*)d_in[5];
    const float* b1      = (const float*)d_in[6];
    const float* fus_w   = (const float*)d_in[7];
    const float* fus_b   = (const float*)d_in[8];
    const float* res_w1  = (const float*)d_in[9];
    const float* res_b1  = (const float*)d_in[10];
    const float* res_w2  = (const float*)d_in[11];
    const float* res_b2  = (const float*)d_in[12];
    const float* head_w1 = (const float*)d_in[13];
    const float* head_b1 = (const float*)d_in[14];
    const float* head_w2 = (const float*)d_in[15];
    const float* head_b2 = (const float*)d_in[16];

    const int N = in_sizes[0] / 2;
    const int nwaves = (N + 15) / 16;
    const int grid = (nwaves + WAVES - 1) / WAVES;

    lstm_pinn_mfma<<<dim3(grid), dim3(TPB), 0, stream>>>(
        xy, w_ih0, w_hh0, b0, w_ih1, w_hh1, b1,
        fus_w, fus_b, res_w1, res_b1, res_w2, res_b2,
        head_w1, head_b1, head_w2, head_b2,
        (float*)d_out, N);
}

// Round 4
// 549.617 us; speedup vs baseline: 22.5023x; 1.4065x over previous
//
#include <hip/hip_runtime.h>
#include <math.h>

#define PI_F 3.14159265358979323846f
#define WAVES 12
#define TPB (WAVES*64)
#define TPB2 512

typedef _Float16 half_t;
typedef __attribute__((ext_vector_type(8))) _Float16 f16x8;
typedef __attribute__((ext_vector_type(4))) float f32x4;

union F16x8U { f16x8 v; unsigned int u[4]; half_t h[8]; };

__device__ __forceinline__ float frcp(float x)  { return __builtin_amdgcn_rcpf(x); }
__device__ __forceinline__ float fsig(float x)  { return frcp(1.0f + __expf(-x)); }
__device__ __forceinline__ float ftanh(float x) { return 1.0f - 2.0f * frcp(1.0f + __expf(2.0f * x)); }

#define MFMA16(a,b,c) __builtin_amdgcn_mfma_f32_16x16x32_f16((a),(b),(c),0,0,0)

// ---- d_ws layout (byte offsets) ----
// REC   @ 0       : recurrent B-frags [3][16][2][64][8] f16        = 98304 B
// AUG   @ 98304   : u32[256] {w_ih0,b0} packed pairs               = 1024 B
// B1    @ 99328   : f32[256] b1                                    = 1024 B
// EPI   @ 100352  : epi frags f16 (fus 6144 | res1 12288 | res2 12288 | hw1 4096 | hw2 1024 halves) = 71680 B
// BIAS  @ 172032  : f32[517] (fus_b 0-63 | res_b1 64-255 | res_b2 256-447 | head_b1 448-511 | head_b2 512-516)
// HOUT  @ 176128  : per-tile final h1 A-frags [ntiles][2][64][8] f16 = ntiles*2048 B
#define AUG_B   98304
#define B1_B    99328
#define EPI_H   50176      // half index
#define BIAS_B  172032
#define HOUT_H  88064      // half index
// epi sub-offsets in halves (relative to EPI)
#define EF_FUS  0
#define EF_R1   6144
#define EF_R2   18432
#define EF_HW1  30720
#define EF_HW2  34816

// ==================== K0: pack all weights ====================
__global__ void pack_weights(const float* __restrict__ w_ih0, const float* __restrict__ w_hh0, const float* __restrict__ b0,
                             const float* __restrict__ w_ih1, const float* __restrict__ w_hh1, const float* __restrict__ b1,
                             const float* __restrict__ fus_w, const float* __restrict__ fus_b,
                             const float* __restrict__ res_w1, const float* __restrict__ res_b1,
                             const float* __restrict__ res_w2, const float* __restrict__ res_b2,
                             const float* __restrict__ head_w1, const float* __restrict__ head_b1,
                             const float* __restrict__ head_w2, const float* __restrict__ head_b2,
                             half_t* __restrict__ hws)
{
    int id = blockIdx.x * blockDim.x + threadIdx.x;

    if (id < 6144) {                       // recurrent B-frags (proven round-3 mapping)
        int ln = id & 63, rest = id >> 6;
        int kb = rest & 1, cb = (rest >> 1) & 15, mat = rest >> 5;
        const float* W = (mat == 0) ? w_hh0 : ((mat == 1) ? w_ih1 : w_hh1);
        const float* src = W + (cb * 16 + (ln & 15)) * 64 + kb * 32 + (ln >> 4) * 8;
        F16x8U t;
        #pragma unroll
        for (int i = 0; i < 8; ++i) t.h[i] = (half_t)src[i];
        *(f16x8*)&hws[id * 8] = t.v;
        return;
    }
    id -= 6144;
    if (id < 256) {                        // aug0 table: {w_ih0[j], b0[j]} as u32
        F16x8U t; t.u[0] = 0;
        t.h[0] = (half_t)w_ih0[id];
        t.h[1] = (half_t)b0[id];
        ((unsigned int*)((char*)hws + AUG_B))[id] = t.u[0];
        return;
    }
    id -= 256;
    if (id < 256) {                        // b1 fp32 copy
        ((float*)((char*)hws + B1_B))[id] = b1[id];
        return;
    }
    id -= 256;
    if (id < 768) {                        // fus frags [cb][kb(3)][64]
        int ln = id & 63, rest = id >> 6;
        int kb = rest % 3, cb = rest / 3;
        int col = cb * 16 + (ln & 15), q = ln >> 4;
        F16x8U t; t.u[0] = t.u[1] = t.u[2] = t.u[3] = 0;
        if (kb < 2) {
            #pragma unroll
            for (int i = 0; i < 8; ++i) t.h[i] = (half_t)fus_w[col * 66 + kb * 32 + q * 8 + i];
        } else if (q == 0) {
            t.h[0] = (half_t)fus_w[col * 66 + 64];
            t.h[1] = (half_t)fus_w[col * 66 + 65];
            t.h[2] = (half_t)fus_b[col];
        }
        *(f16x8*)&hws[(EPI_H + EF_FUS + id * 8)] = t.v;
        return;
    }
    id -= 768;
    if (id < 1536) {                       // res1 frags [rb][cb][kb][64]
        int ln = id & 63, rest = id >> 6;
        int kb = rest & 1, cb = (rest >> 1) & 3, rb = rest >> 3;
        int col = cb * 16 + (ln & 15), q = ln >> 4;
        F16x8U t;
        #pragma unroll
        for (int i = 0; i < 8; ++i) t.h[i] = (half_t)res_w1[rb * 4096 + col * 64 + kb * 32 + q * 8 + i];
        *(f16x8*)&hws[(EPI_H + EF_R1 + id * 8)] = t.v;
        return;
    }
    id -= 1536;
    if (id < 1536) {                       // res2 frags
        int ln = id & 63, rest = id >> 6;
        int kb = rest & 1, cb = (rest >> 1) & 3, rb = rest >> 3;
        int col = cb * 16 + (ln & 15), q = ln >> 4;
        F16x8U t;
        #pragma unroll
        for (int i = 0; i < 8; ++i) t.h[i] = (half_t)res_w2[rb * 4096 + col * 64 + kb * 32 + q * 8 + i];
        *(f16x8*)&hws[(EPI_H + EF_R2 + id * 8)] = t.v;
        return;
    }
    id -= 1536;
    if (id < 512) {                        // head_w1 frags [cb][kb][64]
        int ln = id & 63, rest = id >> 6;
        int kb = rest & 1, cb = rest >> 1;
        int col = cb * 16 + (ln & 15), q = ln >> 4;
        F16x8U t;
        #pragma unroll
        for (int i = 0; i < 8; ++i) t.h[i] = (half_t)head_w1[col * 64 + kb * 32 + q * 8 + i];
        *(f16x8*)&hws[(EPI_H + EF_HW1 + id * 8)] = t.v;
        return;
    }
    id -= 512;
    if (id < 128) {                        // head_w2 frags [kb][64], cols >=5 zero
        int ln = id & 63, kb = id >> 6;
        int col = ln & 15, q = ln >> 4;
        F16x8U t; t.u[0] = t.u[1] = t.u[2] = t.u[3] = 0;
        if (col < 5) {
            #pragma unroll
            for (int i = 0; i < 8; ++i) t.h[i] = (half_t)head_w2[col * 64 + kb * 32 + q * 8 + i];
        }
        *(f16x8*)&hws[(EPI_H + EF_HW2 + id * 8)] = t.v;
        return;
    }
    id -= 128;
    if (id < 517) {                        // biases fp32
        float v;
        if      (id < 64)  v = fus_b[id];
        else if (id < 256) v = res_b1[id - 64];
        else if (id < 448) v = res_b2[id - 256];
        else if (id < 512) v = head_b1[id - 448];
        else               v = head_b2[id - 512];
        ((float*)((char*)hws + BIAS_B))[id] = v;
        return;
    }
}

// ==================== K1: LSTM main loop ====================
__global__ __launch_bounds__(TPB, 3)
void lstm_core(const float* __restrict__ xy, const half_t* __restrict__ hws, int N)
{
    __shared__ __align__(16) half_t wlds[3][16][2][64][8];       // 96 KB
    __shared__ __align__(16) half_t hfrag[WAVES][2][2][64][8];   // 48 KB
    __shared__ unsigned int aug_lds[256];                        // 1 KB
    __shared__ float b1_lds[256];                                // 1 KB

    const int lane = threadIdx.x & 63;
    const int wid  = threadIdx.x >> 6;
    const int cc   = lane & 15;
    const int qq   = lane >> 4;

    // stage pre-packed weights (flat vector copy, no conversion)
    #pragma unroll
    for (int it = 0; it < 8; ++it) {
        int idx = threadIdx.x + it * TPB;    // 0..6143
        *(f16x8*)&((half_t*)wlds)[idx * 8] = *(const f16x8*)&hws[idx * 8];
    }
    if (threadIdx.x < 256) {
        aug_lds[threadIdx.x] = ((const unsigned int*)((const char*)hws + AUG_B))[threadIdx.x];
        b1_lds[threadIdx.x]  = ((const float*)((const char*)hws + B1_B))[threadIdx.x];
    }
    __syncthreads();

    const int tile = blockIdx.x * WAVES + wid;
    const int S = tile * 16;
    if (S >= N) return;

    int si = S + cc; if (si >= N) si = N - 1;
    const float fx = xy[2 * si + 0];
    const float fy = xy[2 * si + 1];
    float feat[9];
    feat[0] = fx; feat[1] = fy; feat[2] = fx * fx; feat[3] = fy * fy; feat[4] = fx * fy;
    feat[5] = sinf(PI_F * fx); feat[6] = cosf(PI_F * fx);
    feat[7] = sinf(PI_F * fy); feat[8] = cosf(PI_F * fy);

    {
        F16x8U Z; Z.u[0] = Z.u[1] = Z.u[2] = Z.u[3] = 0;
        *(f16x8*)&hfrag[wid][0][0][lane][0] = Z.v;
        *(f16x8*)&hfrag[wid][0][1][lane][0] = Z.v;
        *(f16x8*)&hfrag[wid][1][0][lane][0] = Z.v;
        *(f16x8*)&hfrag[wid][1][1][lane][0] = Z.v;
    }
    float c0s[4][4], c1s[4][4];
    #pragma unroll
    for (int a = 0; a < 4; ++a)
        #pragma unroll
        for (int b = 0; b < 4; ++b) { c0s[a][b] = 0.0f; c1s[a][b] = 0.0f; }

    asm volatile("" ::: "memory");

    #pragma unroll 1
    for (int t = 0; t < 9; ++t) {
        float ftv;
        switch (t) {
            case 0: ftv = feat[0]; break;  case 1: ftv = feat[1]; break;
            case 2: ftv = feat[2]; break;  case 3: ftv = feat[3]; break;
            case 4: ftv = feat[4]; break;  case 5: ftv = feat[5]; break;
            case 6: ftv = feat[6]; break;  case 7: ftv = feat[7]; break;
            default: ftv = feat[8]; break;
        }
        F16x8U AG; AG.u[0] = AG.u[1] = AG.u[2] = AG.u[3] = 0;
        if (qq == 0) { AG.h[0] = (half_t)ftv; AG.h[1] = (half_t)1.0f; }

        // ------- layer 0 -------
        f16x8 a00 = *(const f16x8*)&hfrag[wid][0][0][lane][0];
        f16x8 a01 = *(const f16x8*)&hfrag[wid][0][1][lane][0];
        #pragma unroll
        for (int jj = 0; jj < 4; ++jj) {
            f32x4 acc[4];
            #pragma unroll
            for (int g = 0; g < 4; ++g) {
                const int cb = jj + 4 * g;
                F16x8U BA; BA.u[0] = (qq == 0) ? aug_lds[cb * 16 + cc] : 0u;
                BA.u[1] = 0; BA.u[2] = 0; BA.u[3] = 0;
                f32x4 a = {0.f, 0.f, 0.f, 0.f};
                a = MFMA16(AG.v, BA.v, a);
                f16x8 bf0 = *(const f16x8*)&wlds[0][cb][0][lane][0];
                f16x8 bf1 = *(const f16x8*)&wlds[0][cb][1][lane][0];
                a = MFMA16(a00, bf0, a);
                a = MFMA16(a01, bf1, a);
                acc[g] = a;
            }
            const int kb = jj >> 1;
            half_t* hp = &hfrag[wid][0][kb][0][0];
            const int lb = (4 * qq + 16 * ((2 * jj + (cc >> 3)) & 3)) * 8 + (cc & 7);
            #pragma unroll
            for (int r = 0; r < 4; ++r) {
                float gi = fsig(acc[0][r]);
                float gf = fsig(acc[1][r]);
                float gg = ftanh(acc[2][r]);
                float go = fsig(acc[3][r]);
                float cv = gf * c0s[jj][r] + gi * gg;
                c0s[jj][r] = cv;
                hp[lb + 8 * r] = (half_t)(go * ftanh(cv));
            }
        }
        asm volatile("" ::: "memory");

        // ------- layer 1 -------
        f16x8 a10 = *(const f16x8*)&hfrag[wid][0][0][lane][0];
        f16x8 a11 = *(const f16x8*)&hfrag[wid][0][1][lane][0];
        f16x8 a12 = *(const f16x8*)&hfrag[wid][1][0][lane][0];
        f16x8 a13 = *(const f16x8*)&hfrag[wid][1][1][lane][0];
        #pragma unroll
        for (int jj = 0; jj < 4; ++jj) {
            f32x4 acc[4];
            #pragma unroll
            for (int g = 0; g < 4; ++g) {
                const int cb = jj + 4 * g;
                const float bv = b1_lds[cb * 16 + cc];
                f32x4 a = {bv, bv, bv, bv};
                f16x8 bi0 = *(const f16x8*)&wlds[1][cb][0][lane][0];
                f16x8 bi1 = *(const f16x8*)&wlds[1][cb][1][lane][0];
                f16x8 bh0 = *(const f16x8*)&wlds[2][cb][0][lane][0];
                f16x8 bh1 = *(const f16x8*)&wlds[2][cb][1][lane][0];
                a = MFMA16(a10, bi0, a);
                a = MFMA16(a11, bi1, a);
                a = MFMA16(a12, bh0, a);
                a = MFMA16(a13, bh1, a);
                acc[g] = a;
            }
            const int kb = jj >> 1;
            half_t* hp = &hfrag[wid][1][kb][0][0];
            const int lb = (4 * qq + 16 * ((2 * jj + (cc >> 3)) & 3)) * 8 + (cc & 7);
            #pragma unroll
            for (int r = 0; r < 4; ++r) {
                float gi = fsig(acc[0][r]);
                float gf = fsig(acc[1][r]);
                float gg = ftanh(acc[2][r]);
                float go = fsig(acc[3][r]);
                float cv = gf * c1s[jj][r] + gi * gg;
                c1s[jj][r] = cv;
                hp[lb + 8 * r] = (half_t)(go * ftanh(cv));
            }
        }
        asm volatile("" ::: "memory");
    }

    // store final h1 A-frags to workspace (coalesced b128)
    half_t* hout = (half_t*)hws + HOUT_H + (size_t)tile * 1024;
    *(f16x8*)&hout[0   + lane * 8] = *(const f16x8*)&hfrag[wid][1][0][lane][0];
    *(f16x8*)&hout[512 + lane * 8] = *(const f16x8*)&hfrag[wid][1][1][lane][0];
}

// ==================== K2: epilogue MLP ====================
__global__ __launch_bounds__(TPB2, 1)
void epi_mlp(const float* __restrict__ xy, const half_t* __restrict__ hws,
             float* __restrict__ out, int ntiles, int N)
{
    __shared__ __align__(16) half_t ef[35840];                  // 70 KB
    __shared__ float biasl[517];
    __shared__ __align__(16) half_t hbuf[8][2][2][64][8];       // 32 KB

    for (int idx = threadIdx.x; idx < 4480; idx += TPB2)
        *(f16x8*)&ef[idx * 8] = *(const f16x8*)&hws[(EPI_H + idx * 8)];
    const float* bg = (const float*)((const char*)hws + BIAS_B);
    for (int i = threadIdx.x; i < 517; i += TPB2) biasl[i] = bg[i];
    __syncthreads();

    const half_t* hout = hws + HOUT_H;
    const int lane = threadIdx.x & 63;
    const int wid  = threadIdx.x >> 6;
    const int cc   = lane & 15;
    const int qq   = lane >> 4;
    const int gw = blockIdx.x * 8 + wid;
    const int nw = gridDim.x * 8;

#define WRITE_ACT(BUF, VALS) do {                                              \
        _Pragma("unroll")                                                      \
        for (int cb = 0; cb < 4; ++cb) {                                       \
            half_t* hp = &hbuf[wid][BUF][cb >> 1][0][0];                       \
            const int lb = (4*qq + 16*((2*cb + (cc>>3)) & 3))*8 + (cc & 7);    \
            _Pragma("unroll")                                                  \
            for (int r = 0; r < 4; ++r) hp[lb + 8*r] = (half_t)(VALS)[cb][r];  \
        }                                                                      \
        asm volatile("" ::: "memory");                                         \
    } while (0)

    #pragma unroll 1
    for (int tile = gw; tile < ntiles; tile += nw) {
        const size_t hob = (size_t)tile * 1024;
        f16x8 e0 = *(const f16x8*)&hout[hob + lane * 8];
        f16x8 e1 = *(const f16x8*)&hout[hob + 512 + lane * 8];

        int s = tile * 16 + cc; if (s >= N) s = N - 1;
        const float fx = xy[2 * s], fy = xy[2 * s + 1];
        F16x8U AF; AF.u[0] = AF.u[1] = AF.u[2] = AF.u[3] = 0;
        if (qq == 0) { AF.h[0] = (half_t)fx; AF.h[1] = (half_t)fy; AF.h[2] = (half_t)1.0f; }

        // fused layer (bias folded into kb=2 frag)
        float zz[4][4];
        #pragma unroll
        for (int cb = 0; cb < 4; ++cb) {
            f32x4 a = {0.f, 0.f, 0.f, 0.f};
            a = MFMA16(e0,   *(const f16x8*)&ef[(EF_FUS + ((cb * 3 + 0) * 64 + lane) * 8)], a);
            a = MFMA16(e1,   *(const f16x8*)&ef[(EF_FUS + ((cb * 3 + 1) * 64 + lane) * 8)], a);
            a = MFMA16(AF.v, *(const f16x8*)&ef[(EF_FUS + ((cb * 3 + 2) * 64 + lane) * 8)], a);
            #pragma unroll
            for (int r = 0; r < 4; ++r) zz[cb][r] = ftanh(a[r]);
        }
        WRITE_ACT(0, zz);
        f16x8 za0 = *(const f16x8*)&hbuf[wid][0][0][lane][0];
        f16x8 za1 = *(const f16x8*)&hbuf[wid][0][1][lane][0];

        // 3 residual blocks
        #pragma unroll 1
        for (int rb = 0; rb < 3; ++rb) {
            float tt[4][4];
            #pragma unroll
            for (int cb = 0; cb < 4; ++cb) {
                const float bv = biasl[64 + rb * 64 + cb * 16 + cc];
                f32x4 a = {bv, bv, bv, bv};
                a = MFMA16(za0, *(const f16x8*)&ef[(EF_R1 + (((rb * 4 + cb) * 2 + 0) * 64 + lane) * 8)], a);
                a = MFMA16(za1, *(const f16x8*)&ef[(EF_R1 + (((rb * 4 + cb) * 2 + 1) * 64 + lane) * 8)], a);
                #pragma unroll
                for (int r = 0; r < 4; ++r) tt[cb][r] = ftanh(a[r]);
            }
            WRITE_ACT(1, tt);
            f16x8 ta0 = *(const f16x8*)&hbuf[wid][1][0][lane][0];
            f16x8 ta1 = *(const f16x8*)&hbuf[wid][1][1][lane][0];
            #pragma unroll
            for (int cb = 0; cb < 4; ++cb) {
                const float bv = biasl[256 + rb * 64 + cb * 16 + cc];
                f32x4 a = {bv, bv, bv, bv};
                a = MFMA16(ta0, *(const f16x8*)&ef[(EF_R2 + (((rb * 4 + cb) * 2 + 0) * 64 + lane) * 8)], a);
                a = MFMA16(ta1, *(const f16x8*)&ef[(EF_R2 + (((rb * 4 + cb) * 2 + 1) * 64 + lane) * 8)], a);
                #pragma unroll
                for (int r = 0; r < 4; ++r) zz[cb][r] += ftanh(a[r]);
            }
            WRITE_ACT(0, zz);
            za0 = *(const f16x8*)&hbuf[wid][0][0][lane][0];
            za1 = *(const f16x8*)&hbuf[wid][0][1][lane][0];
        }

        // head layer 1
        float hh[4][4];
        #pragma unroll
        for (int cb = 0; cb < 4; ++cb) {
            const float bv = biasl[448 + cb * 16 + cc];
            f32x4 a = {bv, bv, bv, bv};
            a = MFMA16(za0, *(const f16x8*)&ef[(EF_HW1 + ((cb * 2 + 0) * 64 + lane) * 8)], a);
            a = MFMA16(za1, *(const f16x8*)&ef[(EF_HW1 + ((cb * 2 + 1) * 64 + lane) * 8)], a);
            #pragma unroll
            for (int r = 0; r < 4; ++r) hh[cb][r] = ftanh(a[r]);
        }
        WRITE_ACT(1, hh);
        f16x8 ha0 = *(const f16x8*)&hbuf[wid][1][0][lane][0];
        f16x8 ha1 = *(const f16x8*)&hbuf[wid][1][1][lane][0];

        // head layer 2 -> out
        {
            const float bv = (cc < 5) ? biasl[512 + cc] : 0.0f;
            f32x4 a = {bv, bv, bv, bv};
            a = MFMA16(ha0, *(const f16x8*)&ef[(EF_HW2 + ((0) * 64 + lane) * 8)], a);
            a = MFMA16(ha1, *(const f16x8*)&ef[(EF_HW2 + ((1) * 64 + lane) * 8)], a);
            if (cc < 5) {
                #pragma unroll
                for (int r = 0; r < 4; ++r) {
                    const int row = tile * 16 + 4 * qq + r;
                    if (row < N) out[row * 5 + cc] = a[r];
                }
            }
        }
    }
#undef WRITE_ACT
}

extern "C" void kernel_launch(void* const* d_in, const int* in_sizes, int n_in,
                              void* d_out, int out_size, void* d_ws, size_t ws_size,
                              hipStream_t stream) {
    const float* xy      = (const float*)d_in[0];
    const float* w_ih0   = (const float*)d_in[1];
    const float* w_hh0   = (const float*)d_in[2];
    const float* b0      = (const float*)d_in[3];
    const float* w_ih1   = (const float*)d_in[4];
    const float* w_hh1   = (const float*)d_in[5];
    const float* b1      = (const float*)d_in[6];
    const float* fus_w   = (const float*)d_in[7];
    const float* fus_b   = (const float*)d_in[8];
    const float* res_w1  = (const float*)d_in[9];
    const float* res_b1  = (const float*)d_in[10];
    const float* res_w2  = (const float*)d_in[11];
    const float* res_b2  = (const float*)d_in[12];
    const float* head_w1 = (const float*)d_in[13];
    const float* head_b1 = (const float*)d_in[14];
    const float* head_w2 = (const float*)d_in[15];
    const float* head_b2 = (const float*)d_in[16];

    const int N = in_sizes[0] / 2;
    const int ntiles = (N + 15) / 16;
    half_t* hws = (half_t*)d_ws;
    // ws needed: 176128 + ntiles*2048 bytes (~34 MB at N=262144; harness provides >=134 MB)

    // K0: pack weights (11653 tasks)
    pack_weights<<<dim3(46), dim3(256), 0, stream>>>(
        w_ih0, w_hh0, b0, w_ih1, w_hh1, b1,
        fus_w, fus_b, res_w1, res_b1, res_w2, res_b2,
        head_w1, head_b1, head_w2, head_b2, hws);

    // K1: LSTM core
    const int grid1 = (ntiles + WAVES - 1) / WAVES;
    lstm_core<<<dim3(grid1), dim3(TPB), 0, stream>>>(xy, hws, N);

    // K2: epilogue MLP
    epi_mlp<<<dim3(256), dim3(TPB2), 0, stream>>>(xy, hws, (float*)d_out, ntiles, N);
}